// Round 9
// baseline (223.803 us; speedup 1.0000x reference)
//
#include <hip/hip_runtime.h>

#define BLK     512     // 8 waves per block
#define TBATCH  8       // batch rows per block (1 per wave)
#define LLEN    50      // act-list length
#define CONCAT  150     // q+s+v concatenated per row
#define CPAD    152
#define DIM     256     // embedding dim
#define DIM4    64      // DIM / 4 (float4 units)
#define ROWU4Q  16      // uint4 per u8 row (256 B = 16 * 16B)
#define QMASK   0x00FF00FFu

typedef _Float16 half2v __attribute__((ext_vector_type(2)));

__device__ __forceinline__ float sigmoidf_(float x) {
    return 1.0f / (1.0f + __expf(-x));
}
__device__ __forceinline__ half2v bch(unsigned int u) {
    union { unsigned int u; half2v h; } c; c.u = u; return c.h;
}
__device__ __forceinline__ unsigned int pkh(float a, float b) {
    union { half2v h; unsigned int u; } c;
    c.h = half2v{(_Float16)a, (_Float16)b};
    return c.u;
}
__device__ __forceinline__ float hlo(unsigned int u) {
    union { unsigned int u; half2v h; } c; c.u = u; return (float)c.h.x;
}
__device__ __forceinline__ float hhi(unsigned int u) {
    union { unsigned int u; half2v h; } c; c.u = u; return (float)c.h.y;
}

// ---- prep: blocks [0,32) pack w1/w2 -> f16 tile; rest convert emb -> u8 ----
// wpk[j4*256 + i] = uint4{ h2(w1[i][4j4],w1[i][4j4+1]), h2(w1[i][4j4+2],w1[i][4j4+3]),
//                          h2(w2[i][4j4],w2[i][4j4+1]), h2(w2[i][4j4+2],w2[i][4j4+3]) }
__global__ __launch_bounds__(512) void prep_kernel(
    const float* __restrict__ w1, const float* __restrict__ w2,
    const float* __restrict__ emb,
    uint4* __restrict__ wpk,
    uint4* __restrict__ embq, int nelem)
{
    if (blockIdx.x < 32) {
        const int idx = blockIdx.x * 512 + threadIdx.x;   // [0, 16384)
        const int j4  = idx >> 8;
        const int i   = idx & 255;
        float4 a = ((const float4*)(w1 + i * DIM))[j4];
        float4 b = ((const float4*)(w2 + i * DIM))[j4];
        wpk[idx] = make_uint4(pkh(a.x, a.y), pkh(a.z, a.w),
                              pkh(b.x, b.y), pkh(b.z, b.w));
    } else {
        // each thread converts 16 consecutive floats -> one uint4 of u8
        const int base = (blockIdx.x - 32) * (512 * 16) + threadIdx.x * 16;
        if (base < nelem) {
            const float4* e4 = (const float4*)(emb + base);
            unsigned int wds[4];
            #pragma unroll
            for (int k = 0; k < 4; k++) {
                float4 a = e4[k];
                unsigned int b0 = __float2uint_rn(fminf(fmaxf(a.x * 32.f + 128.f, 0.f), 255.f));
                unsigned int b1 = __float2uint_rn(fminf(fmaxf(a.y * 32.f + 128.f, 0.f), 255.f));
                unsigned int b2 = __float2uint_rn(fminf(fmaxf(a.z * 32.f + 128.f, 0.f), 255.f));
                unsigned int b3 = __float2uint_rn(fminf(fmaxf(a.w * 32.f + 128.f, 0.f), 255.f));
                wds[k] = b0 | (b1 << 8) | (b2 << 16) | (b3 << 24);
            }
            embq[base >> 4] = make_uint4(wds[0], wds[1], wds[2], wds[3]);
        }
    }
}

template<bool QU8>
__global__ __launch_bounds__(BLK, 8) void slotgate_fused(
    const int* __restrict__ acts_request,   // (B, 50)
    const int* __restrict__ acts_slot,      // (B, 50)
    const int* __restrict__ acts_value,     // (B, 50)
    const int* __restrict__ slot_names,     // (B, 4)
    const float* __restrict__ emb,          // (V, 256) fp32 (c_s + fallback)
    const uint4* __restrict__ embq,         // (V, 256) u8 quantized
    const uint4* __restrict__ wpk,          // f16-packed w1|w2 tile [j4][i]
    float* __restrict__ out)                // (B, 4, 256)
{
    __shared__ int          lds_idx[TBATCH * CPAD];  // concat q|s|v per row
    __shared__ uint4        lds_t  [TBATCH * DIM4];  // f16 pairs: tq x4 | tsv x4 per j4
    __shared__ unsigned int lds_g  [TBATCH * DIM];   // f16 pair (g_q, g_sv) per (row,i)

    const int tid  = threadIdx.x;
    const int b0   = blockIdx.x * TBATCH;
    const int wv   = tid >> 6;    // 0..7 == batch row within block
    const int lane = tid & 63;

    // ---- stage concatenated indices ----
    for (int t = tid; t < TBATCH * CONCAT; t += BLK) {
        const int row = t / CONCAT;
        const int e   = t - row * CONCAT;
        const int b   = b0 + row;
        int idx;
        if      (e < 50)  idx = acts_request[b * LLEN + e];
        else if (e < 100) idx = acts_slot   [b * LLEN + e - 50];
        else              idx = acts_value  [b * LLEN + e - 100];
        lds_idx[row * CPAD + e] = idx;
    }
    __syncthreads();

    const float4* emb4 = (const float4*)emb;

    // ---- gather: wave wv owns batch row (b0+wv) ----
    if (QU8) {
        // 4 list-entries per 1KB wave-load; exact packed-u16 integer accumulation.
        const int g   = lane >> 4;
        const int hl  = lane & 15;
        const int* ip = &lds_idx[wv * CPAD];
        unsigned int qe[4] = {}, qo[4] = {};    // t_q  even/odd byte accs
        unsigned int se[4] = {}, so[4] = {};    // t_sv even/odd byte accs
        #pragma unroll 4
        for (int m = 0; m < 12; m++) {
            uint4 p = embq[ip[4 * m + g] * ROWU4Q + hl];
            qe[0] += p.x & QMASK; qo[0] += (p.x >> 8) & QMASK;
            qe[1] += p.y & QMASK; qo[1] += (p.y >> 8) & QMASK;
            qe[2] += p.z & QMASK; qo[2] += (p.z >> 8) & QMASK;
            qe[3] += p.w & QMASK; qo[3] += (p.w >> 8) & QMASK;
        }
        if (lane < 32) {
            uint4 p = embq[ip[48 + g] * ROWU4Q + hl];
            qe[0] += p.x & QMASK; qo[0] += (p.x >> 8) & QMASK;
            qe[1] += p.y & QMASK; qo[1] += (p.y >> 8) & QMASK;
            qe[2] += p.z & QMASK; qo[2] += (p.z >> 8) & QMASK;
            qe[3] += p.w & QMASK; qo[3] += (p.w >> 8) & QMASK;
        }
        #pragma unroll 5
        for (int m = 0; m < 25; m++) {
            uint4 p = embq[ip[50 + 4 * m + g] * ROWU4Q + hl];
            se[0] += p.x & QMASK; so[0] += (p.x >> 8) & QMASK;
            se[1] += p.y & QMASK; so[1] += (p.y >> 8) & QMASK;
            se[2] += p.z & QMASK; so[2] += (p.z >> 8) & QMASK;
            se[3] += p.w & QMASK; so[3] += (p.w >> 8) & QMASK;
        }
        #pragma unroll
        for (int w = 0; w < 4; w++) {
            qe[w] += __shfl_xor(qe[w], 16, 64); qe[w] += __shfl_xor(qe[w], 32, 64);
            qo[w] += __shfl_xor(qo[w], 16, 64); qo[w] += __shfl_xor(qo[w], 32, 64);
            se[w] += __shfl_xor(se[w], 16, 64); se[w] += __shfl_xor(se[w], 32, 64);
            so[w] += __shfl_xor(so[w], 16, 64); so[w] += __shfl_xor(so[w], 32, 64);
        }
        // lanes 0..15: bias-correct (q = 32x+128), scale 1/32, pack f16 pairs
        if (lane < 16) {
            #pragma unroll
            for (int w = 0; w < 4; w++) {
                float tq0 = (float)((int)(qe[w] & 0xFFFFu) - 6400)  * 0.03125f;
                float tq1 = (float)((int)(qo[w] & 0xFFFFu) - 6400)  * 0.03125f;
                float tq2 = (float)((int)(qe[w] >> 16)     - 6400)  * 0.03125f;
                float tq3 = (float)((int)(qo[w] >> 16)     - 6400)  * 0.03125f;
                float ts0 = (float)((int)(se[w] & 0xFFFFu) - 12800) * 0.03125f;
                float ts1 = (float)((int)(so[w] & 0xFFFFu) - 12800) * 0.03125f;
                float ts2 = (float)((int)(se[w] >> 16)     - 12800) * 0.03125f;
                float ts3 = (float)((int)(so[w] >> 16)     - 12800) * 0.03125f;
                lds_t[wv * DIM4 + hl * 4 + w] =
                    make_uint4(pkh(tq0, tq1), pkh(tq2, tq3),
                               pkh(ts0, ts1), pkh(ts2, ts3));
            }
        }
    } else {
        const int* ip = &lds_idx[wv * CPAD];
        float4 aq  = make_float4(0.f, 0.f, 0.f, 0.f);
        float4 asv = make_float4(0.f, 0.f, 0.f, 0.f);
        #pragma unroll 10
        for (int e = 0; e < 50; e++) {
            float4 v = emb4[ip[e] * DIM4 + lane];
            aq.x += v.x; aq.y += v.y; aq.z += v.z; aq.w += v.w;
        }
        #pragma unroll 10
        for (int e = 50; e < 150; e++) {
            float4 v = emb4[ip[e] * DIM4 + lane];
            asv.x += v.x; asv.y += v.y; asv.z += v.z; asv.w += v.w;
        }
        lds_t[wv * DIM4 + lane] =
            make_uint4(pkh(aq.x, aq.y), pkh(aq.z, aq.w),
                       pkh(asv.x, asv.y), pkh(asv.z, asv.w));
    }
    __syncthreads();

    // ---- matmul: thread owns i = tid&255 and 4 batch rows; f16 dot2 ----
    {
        const int i  = tid & 255;
        const int r0 = (tid >> 8) * 4;       // wave-uniform: 0 or 4
        float accq [4] = {};
        float accsv[4] = {};
        #pragma unroll 8
        for (int j4 = 0; j4 < DIM4; j4++) {
            const uint4 wp = wpk[j4 * 256 + i];   // 1 coalesced dwordx4/thread
            #pragma unroll
            for (int r = 0; r < 4; r++) {
                const uint4 tp = lds_t[(r0 + r) * DIM4 + j4];  // uniform b128
                accq [r] = __builtin_amdgcn_fdot2(bch(wp.x), bch(tp.x), accq [r], false);
                accq [r] = __builtin_amdgcn_fdot2(bch(wp.y), bch(tp.y), accq [r], false);
                accsv[r] = __builtin_amdgcn_fdot2(bch(wp.z), bch(tp.z), accsv[r], false);
                accsv[r] = __builtin_amdgcn_fdot2(bch(wp.w), bch(tp.w), accsv[r], false);
            }
        }
        #pragma unroll
        for (int r = 0; r < 4; r++)
            lds_g[(r0 + r) * DIM + i] = pkh(accq[r], accsv[r]);
    }
    __syncthreads();

    // ---- epilogue: gates = c_s + sig(c_s*g_q) + sig(c_s*g_sv); c_s exact fp32 ----
    {
        const uint4* gp4 = (const uint4*)lds_g;
        float4* out4 = (float4*)out;
        #pragma unroll
        for (int t = tid; t < TBATCH * 4 * DIM4; t += BLK) {
            const int row = t >> 8;
            const int s   = (t >> 6) & 3;
            const int col = t & 63;
            const int b   = b0 + row;
            const int slot = slot_names[b * 4 + s];
            float4 cs = emb4[slot * DIM4 + col];
            uint4 gp = gp4[row * DIM4 + col];    // (gq,gsv) for i=4col..4col+3
            float4 g;
            g.x = cs.x + sigmoidf_(cs.x * hlo(gp.x)) + sigmoidf_(cs.x * hhi(gp.x));
            g.y = cs.y + sigmoidf_(cs.y * hlo(gp.y)) + sigmoidf_(cs.y * hhi(gp.y));
            g.z = cs.z + sigmoidf_(cs.z * hlo(gp.z)) + sigmoidf_(cs.z * hhi(gp.z));
            g.w = cs.w + sigmoidf_(cs.w * hlo(gp.w)) + sigmoidf_(cs.w * hhi(gp.w));
            out4[(b * 4 + s) * DIM4 + col] = g;
        }
    }
}

extern "C" void kernel_launch(void* const* d_in, const int* in_sizes, int n_in,
                              void* d_out, int out_size, void* d_ws, size_t ws_size,
                              hipStream_t stream) {
    const int*   acts_request = (const int*)  d_in[0];
    const int*   acts_slot    = (const int*)  d_in[1];
    const int*   acts_value   = (const int*)  d_in[2];
    const int*   slot_names   = (const int*)  d_in[3];
    const float* ontology_emb = (const float*)d_in[4];
    const float* w1           = (const float*)d_in[5];
    const float* w2           = (const float*)d_in[6];
    float*       out          = (float*)      d_out;

    const int bsz   = in_sizes[0] / LLEN;        // 4096
    const int nblk  = bsz / TBATCH;              // 512
    const int nelem = in_sizes[4];               // V * 256 = 25,600,000

    const size_t q_bytes = (size_t)nelem;        // 25.6 MB
    const size_t w_bytes = (size_t)DIM4 * DIM * 16;  // 256 KB packed f16 tile
    const bool   use_q   = ws_size >= q_bytes + w_bytes;

    if (use_q) {
        uint4* embq = (uint4*)d_ws;
        uint4* wpk  = (uint4*)((char*)d_ws + q_bytes);
        const int conv_blocks = (nelem + (512 * 16) - 1) / (512 * 16);
        prep_kernel<<<32 + conv_blocks, 512, 0, stream>>>(
            w1, w2, ontology_emb, wpk, embq, nelem);
        slotgate_fused<true><<<nblk, BLK, 0, stream>>>(
            acts_request, acts_slot, acts_value, slot_names,
            ontology_emb, embq, wpk, out);
    } else {
        // fallback: fp32 gather, but still needs the 256 KB packed-w tile
        uint4* wpk = (uint4*)d_ws;
        prep_kernel<<<32, 512, 0, stream>>>(
            w1, w2, ontology_emb, wpk, (uint4*)d_ws, 0);
        slotgate_fused<false><<<nblk, BLK, 0, stream>>>(
            acts_request, acts_slot, acts_value, slot_names,
            ontology_emb, (const uint4*)d_ws, wpk, out);
    }
}

// Round 10
// 209.819 us; speedup vs baseline: 1.0667x; 1.0667x over previous
//
#include <hip/hip_runtime.h>

#define BLK     256     // 4 waves per block
#define TBATCH  4       // batch rows per block (1 per wave)
#define LLEN    50      // act-list length
#define CONCAT  150     // q+s+v concatenated per row
#define CPAD    152
#define DIM     256     // embedding dim
#define DIM4    64      // DIM / 4 (float4 units)
#define ROWU4Q  16      // uint4 per u8 row (256 B = 16 * 16B)
#define QMASK   0x00FF00FFu

typedef _Float16 half2v __attribute__((ext_vector_type(2)));

__device__ __forceinline__ float sigmoidf_(float x) {
    return 1.0f / (1.0f + __expf(-x));
}
__device__ __forceinline__ half2v bch(unsigned int u) {
    union { unsigned int u; half2v h; } c; c.u = u; return c.h;
}
__device__ __forceinline__ unsigned int pkh(float a, float b) {
    union { half2v h; unsigned int u; } c;
    c.h = half2v{(_Float16)a, (_Float16)b};
    return c.u;
}

// ---- prep: blocks [0,32) pack w1/w2 -> f16 tile; rest convert emb -> u8 ----
// wpk[j4*256 + i] = uint4{ h2(w1[i][4j4..]), h2(w1[i][4j4+2..]),
//                          h2(w2[i][4j4..]), h2(w2[i][4j4+2..]) }
__global__ __launch_bounds__(512) void prep_kernel(
    const float* __restrict__ w1, const float* __restrict__ w2,
    const float* __restrict__ emb,
    uint4* __restrict__ wpk,
    uint4* __restrict__ embq, int nelem)
{
    if (blockIdx.x < 32) {
        const int idx = blockIdx.x * 512 + threadIdx.x;   // [0, 16384)
        const int j4  = idx >> 8;
        const int i   = idx & 255;
        float4 a = ((const float4*)(w1 + i * DIM))[j4];
        float4 b = ((const float4*)(w2 + i * DIM))[j4];
        wpk[idx] = make_uint4(pkh(a.x, a.y), pkh(a.z, a.w),
                              pkh(b.x, b.y), pkh(b.z, b.w));
    } else {
        // each thread converts 16 consecutive floats -> one uint4 of u8
        const int base = (blockIdx.x - 32) * (512 * 16) + threadIdx.x * 16;
        if (base < nelem) {
            const float4* e4 = (const float4*)(emb + base);
            unsigned int wds[4];
            #pragma unroll
            for (int k = 0; k < 4; k++) {
                float4 a = e4[k];
                unsigned int b0 = __float2uint_rn(fminf(fmaxf(a.x * 32.f + 128.f, 0.f), 255.f));
                unsigned int b1 = __float2uint_rn(fminf(fmaxf(a.y * 32.f + 128.f, 0.f), 255.f));
                unsigned int b2 = __float2uint_rn(fminf(fmaxf(a.z * 32.f + 128.f, 0.f), 255.f));
                unsigned int b3 = __float2uint_rn(fminf(fmaxf(a.w * 32.f + 128.f, 0.f), 255.f));
                wds[k] = b0 | (b1 << 8) | (b2 << 16) | (b3 << 24);
            }
            embq[base >> 4] = make_uint4(wds[0], wds[1], wds[2], wds[3]);
        }
    }
}

template<bool QU8>
__global__ __launch_bounds__(BLK, 8) void slotgate_fused(
    const int* __restrict__ acts_request,   // (B, 50)
    const int* __restrict__ acts_slot,      // (B, 50)
    const int* __restrict__ acts_value,     // (B, 50)
    const int* __restrict__ slot_names,     // (B, 4)
    const float* __restrict__ emb,          // (V, 256) fp32 (c_s + fallback)
    const uint4* __restrict__ embq,         // (V, 256) u8 quantized
    const uint4* __restrict__ wpk,          // f16-packed w1|w2 tile [j4][i]
    float* __restrict__ out)                // (B, 4, 256)
{
    __shared__ int   lds_idx[TBATCH * CPAD];   // concat q|s|v per row
    __shared__ uint4 lds_t  [TBATCH * DIM4];   // f16 pairs: tq x4 | tsv x4 per j4
    __shared__ float lds_gq [TBATCH * DIM];    // g_q  [row][i]
    __shared__ float lds_gsv[TBATCH * DIM];    // g_sv [row][i]

    const int tid  = threadIdx.x;
    const int b0   = blockIdx.x * TBATCH;
    const int wv   = tid >> 6;    // 0..3 == batch row within block
    const int lane = tid & 63;

    // ---- stage concatenated indices ----
    for (int t = tid; t < TBATCH * CONCAT; t += BLK) {
        const int row = t / CONCAT;
        const int e   = t - row * CONCAT;
        const int b   = b0 + row;
        int idx;
        if      (e < 50)  idx = acts_request[b * LLEN + e];
        else if (e < 100) idx = acts_slot   [b * LLEN + e - 50];
        else              idx = acts_value  [b * LLEN + e - 100];
        lds_idx[row * CPAD + e] = idx;
    }
    __syncthreads();

    const float4* emb4 = (const float4*)emb;

    // ---- gather: wave wv owns batch row (b0+wv) ----
    if (QU8) {
        // 4 list-entries per 1KB wave-load; exact packed-u16 integer accumulation.
        const int g   = lane >> 4;
        const int hl  = lane & 15;
        const int* ip = &lds_idx[wv * CPAD];
        unsigned int qe[4] = {}, qo[4] = {};    // t_q  even/odd byte accs
        unsigned int se[4] = {}, so[4] = {};    // t_sv even/odd byte accs
        #pragma unroll 4
        for (int m = 0; m < 12; m++) {
            uint4 p = embq[ip[4 * m + g] * ROWU4Q + hl];
            qe[0] += p.x & QMASK; qo[0] += (p.x >> 8) & QMASK;
            qe[1] += p.y & QMASK; qo[1] += (p.y >> 8) & QMASK;
            qe[2] += p.z & QMASK; qo[2] += (p.z >> 8) & QMASK;
            qe[3] += p.w & QMASK; qo[3] += (p.w >> 8) & QMASK;
        }
        if (lane < 32) {
            uint4 p = embq[ip[48 + g] * ROWU4Q + hl];
            qe[0] += p.x & QMASK; qo[0] += (p.x >> 8) & QMASK;
            qe[1] += p.y & QMASK; qo[1] += (p.y >> 8) & QMASK;
            qe[2] += p.z & QMASK; qo[2] += (p.z >> 8) & QMASK;
            qe[3] += p.w & QMASK; qo[3] += (p.w >> 8) & QMASK;
        }
        #pragma unroll 5
        for (int m = 0; m < 25; m++) {
            uint4 p = embq[ip[50 + 4 * m + g] * ROWU4Q + hl];
            se[0] += p.x & QMASK; so[0] += (p.x >> 8) & QMASK;
            se[1] += p.y & QMASK; so[1] += (p.y >> 8) & QMASK;
            se[2] += p.z & QMASK; so[2] += (p.z >> 8) & QMASK;
            se[3] += p.w & QMASK; so[3] += (p.w >> 8) & QMASK;
        }
        #pragma unroll
        for (int w = 0; w < 4; w++) {
            qe[w] += __shfl_xor(qe[w], 16, 64); qe[w] += __shfl_xor(qe[w], 32, 64);
            qo[w] += __shfl_xor(qo[w], 16, 64); qo[w] += __shfl_xor(qo[w], 32, 64);
            se[w] += __shfl_xor(se[w], 16, 64); se[w] += __shfl_xor(se[w], 32, 64);
            so[w] += __shfl_xor(so[w], 16, 64); so[w] += __shfl_xor(so[w], 32, 64);
        }
        // lanes 0..15: bias-correct (q = 32x+128), scale 1/32, pack f16 pairs
        if (lane < 16) {
            #pragma unroll
            for (int w = 0; w < 4; w++) {
                float tq0 = (float)((int)(qe[w] & 0xFFFFu) - 6400)  * 0.03125f;
                float tq1 = (float)((int)(qo[w] & 0xFFFFu) - 6400)  * 0.03125f;
                float tq2 = (float)((int)(qe[w] >> 16)     - 6400)  * 0.03125f;
                float tq3 = (float)((int)(qo[w] >> 16)     - 6400)  * 0.03125f;
                float ts0 = (float)((int)(se[w] & 0xFFFFu) - 12800) * 0.03125f;
                float ts1 = (float)((int)(so[w] & 0xFFFFu) - 12800) * 0.03125f;
                float ts2 = (float)((int)(se[w] >> 16)     - 12800) * 0.03125f;
                float ts3 = (float)((int)(so[w] >> 16)     - 12800) * 0.03125f;
                lds_t[wv * DIM4 + hl * 4 + w] =
                    make_uint4(pkh(tq0, tq1), pkh(tq2, tq3),
                               pkh(ts0, ts1), pkh(ts2, ts3));
            }
        }
    } else {
        const int* ip = &lds_idx[wv * CPAD];
        float4 aq  = make_float4(0.f, 0.f, 0.f, 0.f);
        float4 asv = make_float4(0.f, 0.f, 0.f, 0.f);
        #pragma unroll 10
        for (int e = 0; e < 50; e++) {
            float4 v = emb4[ip[e] * DIM4 + lane];
            aq.x += v.x; aq.y += v.y; aq.z += v.z; aq.w += v.w;
        }
        #pragma unroll 10
        for (int e = 50; e < 150; e++) {
            float4 v = emb4[ip[e] * DIM4 + lane];
            asv.x += v.x; asv.y += v.y; asv.z += v.z; asv.w += v.w;
        }
        lds_t[wv * DIM4 + lane] =
            make_uint4(pkh(aq.x, aq.y), pkh(aq.z, aq.w),
                       pkh(asv.x, asv.y), pkh(asv.z, asv.w));
    }
    __syncthreads();

    // ---- matmul: thread owns i = tid (0..255) and all 4 batch rows ----
    {
        const int i = tid;
        float accq [4] = {};
        float accsv[4] = {};
        #pragma unroll 4
        for (int j4 = 0; j4 < DIM4; j4++) {
            const uint4 wp = wpk[j4 * 256 + i];   // 1 coalesced dwordx4/thread
            #pragma unroll
            for (int r = 0; r < 4; r++) {
                const uint4 tp = lds_t[r * DIM4 + j4];  // uniform b128
                accq [r] = __builtin_amdgcn_fdot2(bch(wp.x), bch(tp.x), accq [r], false);
                accq [r] = __builtin_amdgcn_fdot2(bch(wp.y), bch(tp.y), accq [r], false);
                accsv[r] = __builtin_amdgcn_fdot2(bch(wp.z), bch(tp.z), accsv[r], false);
                accsv[r] = __builtin_amdgcn_fdot2(bch(wp.w), bch(tp.w), accsv[r], false);
            }
        }
        #pragma unroll
        for (int r = 0; r < 4; r++) {
            lds_gq [r * DIM + i] = accq [r];
            lds_gsv[r * DIM + i] = accsv[r];
        }
    }
    __syncthreads();

    // ---- epilogue: gates = c_s + sig(c_s*g_q) + sig(c_s*g_sv); c_s exact fp32 ----
    {
        const float4* gq4 = (const float4*)lds_gq;
        const float4* gs4 = (const float4*)lds_gsv;
        float4* out4 = (float4*)out;
        #pragma unroll
        for (int t = tid; t < TBATCH * 4 * DIM4; t += BLK) {
            const int row = t >> 8;
            const int s   = (t >> 6) & 3;
            const int col = t & 63;
            const int b   = b0 + row;
            const int slot = slot_names[b * 4 + s];
            float4 cs = emb4[slot * DIM4 + col];
            float4 gq = gq4[row * DIM4 + col];
            float4 gs = gs4[row * DIM4 + col];
            float4 g;
            g.x = cs.x + sigmoidf_(cs.x * gq.x) + sigmoidf_(cs.x * gs.x);
            g.y = cs.y + sigmoidf_(cs.y * gq.y) + sigmoidf_(cs.y * gs.y);
            g.z = cs.z + sigmoidf_(cs.z * gq.z) + sigmoidf_(cs.z * gs.z);
            g.w = cs.w + sigmoidf_(cs.w * gq.w) + sigmoidf_(cs.w * gs.w);
            out4[(b * 4 + s) * DIM4 + col] = g;
        }
    }
}

extern "C" void kernel_launch(void* const* d_in, const int* in_sizes, int n_in,
                              void* d_out, int out_size, void* d_ws, size_t ws_size,
                              hipStream_t stream) {
    const int*   acts_request = (const int*)  d_in[0];
    const int*   acts_slot    = (const int*)  d_in[1];
    const int*   acts_value   = (const int*)  d_in[2];
    const int*   slot_names   = (const int*)  d_in[3];
    const float* ontology_emb = (const float*)d_in[4];
    const float* w1           = (const float*)d_in[5];
    const float* w2           = (const float*)d_in[6];
    float*       out          = (float*)      d_out;

    const int bsz   = in_sizes[0] / LLEN;        // 4096
    const int nblk  = bsz / TBATCH;              // 1024
    const int nelem = in_sizes[4];               // V * 256 = 25,600,000

    const size_t q_bytes = (size_t)nelem;        // 25.6 MB
    const size_t w_bytes = (size_t)DIM4 * DIM * 16;  // 256 KB packed f16 tile
    const bool   use_q   = ws_size >= q_bytes + w_bytes;

    if (use_q) {
        uint4* embq = (uint4*)d_ws;
        uint4* wpk  = (uint4*)((char*)d_ws + q_bytes);
        const int conv_blocks = (nelem + (512 * 16) - 1) / (512 * 16);
        prep_kernel<<<32 + conv_blocks, 512, 0, stream>>>(
            w1, w2, ontology_emb, wpk, embq, nelem);
        slotgate_fused<true><<<nblk, BLK, 0, stream>>>(
            acts_request, acts_slot, acts_value, slot_names,
            ontology_emb, embq, wpk, out);
    } else {
        // fallback: fp32 gather, but still needs the 256 KB packed-w tile
        uint4* wpk = (uint4*)d_ws;
        prep_kernel<<<32, 512, 0, stream>>>(
            w1, w2, ontology_emb, wpk, (uint4*)d_ws, 0);
        slotgate_fused<false><<<nblk, BLK, 0, stream>>>(
            acts_request, acts_slot, acts_value, slot_names,
            ontology_emb, (const uint4*)d_ws, wpk, out);
    }
}

// Round 12
// 206.804 us; speedup vs baseline: 1.0822x; 1.0146x over previous
//
#include <hip/hip_runtime.h>

#define BLK     256     // 4 waves per block
#define TBATCH  4       // batch rows per block (1 per wave)
#define LLEN    50      // act-list length
#define CONCAT  150     // q+s+v concatenated per row
#define CPAD    152
#define DIM     256     // embedding dim
#define DIM4    64      // DIM / 4 (float4 units)
#define ROWU4Q  16      // uint4 per u8 row (256 B = 16 * 16B)
#define QMASK   0x00FF00FFu

typedef _Float16 half2v __attribute__((ext_vector_type(2)));

__device__ __forceinline__ float sigmoidf_(float x) {
    return 1.0f / (1.0f + __expf(-x));
}
__device__ __forceinline__ half2v bch(unsigned int u) {
    union { unsigned int u; half2v h; } c; c.u = u; return c.h;
}
__device__ __forceinline__ unsigned int pkh(float a, float b) {
    union { half2v h; unsigned int u; } c;
    c.h = half2v{(_Float16)a, (_Float16)b};
    return c.u;
}

// ---- prep: blocks [0,32) pack w1/w2 -> f16 tile; rest convert emb -> u8 ----
// NOTE: u8 range is [-4, +3.97]; fine for the gather (clipping averages out,
// passes through sigmoid) but NEVER use it for the linear c_s term (r11 bug).
__global__ __launch_bounds__(512) void prep_kernel(
    const float* __restrict__ w1, const float* __restrict__ w2,
    const float* __restrict__ emb,
    uint4* __restrict__ wpk,
    uint4* __restrict__ embq, int nelem)
{
    if (blockIdx.x < 32) {
        const int idx = blockIdx.x * 512 + threadIdx.x;   // [0, 16384)
        const int j4  = idx >> 8;
        const int i   = idx & 255;
        float4 a = ((const float4*)(w1 + i * DIM))[j4];
        float4 b = ((const float4*)(w2 + i * DIM))[j4];
        wpk[idx] = make_uint4(pkh(a.x, a.y), pkh(a.z, a.w),
                              pkh(b.x, b.y), pkh(b.z, b.w));
    } else {
        // each thread converts 16 consecutive floats -> one uint4 of u8
        const int base = (blockIdx.x - 32) * (512 * 16) + threadIdx.x * 16;
        if (base < nelem) {
            const float4* e4 = (const float4*)(emb + base);
            unsigned int wds[4];
            #pragma unroll
            for (int k = 0; k < 4; k++) {
                float4 a = e4[k];
                unsigned int b0 = __float2uint_rn(fminf(fmaxf(a.x * 32.f + 128.f, 0.f), 255.f));
                unsigned int b1 = __float2uint_rn(fminf(fmaxf(a.y * 32.f + 128.f, 0.f), 255.f));
                unsigned int b2 = __float2uint_rn(fminf(fmaxf(a.z * 32.f + 128.f, 0.f), 255.f));
                unsigned int b3 = __float2uint_rn(fminf(fmaxf(a.w * 32.f + 128.f, 0.f), 255.f));
                wds[k] = b0 | (b1 << 8) | (b2 << 16) | (b3 << 24);
            }
            embq[base >> 4] = make_uint4(wds[0], wds[1], wds[2], wds[3]);
        }
    }
}

template<bool QU8>
__global__ __launch_bounds__(BLK, 8) void slotgate_fused(
    const int* __restrict__ acts_request,   // (B, 50)
    const int* __restrict__ acts_slot,      // (B, 50)
    const int* __restrict__ acts_value,     // (B, 50)
    const int* __restrict__ slot_names,     // (B, 4)
    const float* __restrict__ emb,          // (V, 256) fp32 (exact c_s)
    const uint4* __restrict__ embq,         // (V, 256) u8 quantized (gather)
    const uint4* __restrict__ wpk,          // f16-packed w1|w2 tile [j4][i]
    float* __restrict__ out)                // (B, 4, 256)
{
    __shared__ int    lds_idx[TBATCH * CPAD];      // concat q|s|v per row
    __shared__ uint4  lds_t  [TBATCH * DIM4];      // f16 pairs: tq x4 | tsv x4
    __shared__ float  lds_gq [TBATCH * DIM];       // g_q  [row][i]
    __shared__ float  lds_gsv[TBATCH * DIM];       // g_sv [row][i]
    __shared__ float4 lds_cs [TBATCH * 4 * DIM4];  // exact fp32 c_s (16 rows, 16KB)

    const int tid  = threadIdx.x;
    const int b0   = blockIdx.x * TBATCH;
    const int wv   = tid >> 6;    // 0..3 == batch row within block
    const int lane = tid & 63;

    const float4* emb4 = (const float4*)emb;

    // ---- prefetch exact fp32 c_s rows into LDS; latency hides under gather ----
    if (QU8) {
        #pragma unroll
        for (int k = 0; k < 4; k++) {
            const int e = tid + k * 256;     // 0..1023
            const int r = e >> 6;            // 0..15 = row*4 + s
            const int c = e & 63;            // float4 col; coalesced per wave
            const int slot = slot_names[b0 * 4 + r];
            lds_cs[r * DIM4 + c] = emb4[slot * DIM4 + c];
        }
    }

    // ---- stage concatenated indices ----
    for (int t = tid; t < TBATCH * CONCAT; t += BLK) {
        const int row = t / CONCAT;
        const int e   = t - row * CONCAT;
        const int b   = b0 + row;
        int idx;
        if      (e < 50)  idx = acts_request[b * LLEN + e];
        else if (e < 100) idx = acts_slot   [b * LLEN + e - 50];
        else              idx = acts_value  [b * LLEN + e - 100];
        lds_idx[row * CPAD + e] = idx;
    }
    __syncthreads();

    // ---- gather: wave wv owns batch row (b0+wv) ----
    if (QU8) {
        // 4 list-entries per 1KB wave-load; exact packed-u16 integer accumulation.
        const int g   = lane >> 4;
        const int hl  = lane & 15;
        const int* ip = &lds_idx[wv * CPAD];
        unsigned int qe[4] = {}, qo[4] = {};    // t_q  even/odd byte accs
        unsigned int se[4] = {}, so[4] = {};    // t_sv even/odd byte accs
        #pragma unroll 4
        for (int m = 0; m < 12; m++) {
            uint4 p = embq[ip[4 * m + g] * ROWU4Q + hl];
            qe[0] += p.x & QMASK; qo[0] += (p.x >> 8) & QMASK;
            qe[1] += p.y & QMASK; qo[1] += (p.y >> 8) & QMASK;
            qe[2] += p.z & QMASK; qo[2] += (p.z >> 8) & QMASK;
            qe[3] += p.w & QMASK; qo[3] += (p.w >> 8) & QMASK;
        }
        if (lane < 32) {
            uint4 p = embq[ip[48 + g] * ROWU4Q + hl];
            qe[0] += p.x & QMASK; qo[0] += (p.x >> 8) & QMASK;
            qe[1] += p.y & QMASK; qo[1] += (p.y >> 8) & QMASK;
            qe[2] += p.z & QMASK; qo[2] += (p.z >> 8) & QMASK;
            qe[3] += p.w & QMASK; qo[3] += (p.w >> 8) & QMASK;
        }
        #pragma unroll 5
        for (int m = 0; m < 25; m++) {
            uint4 p = embq[ip[50 + 4 * m + g] * ROWU4Q + hl];
            se[0] += p.x & QMASK; so[0] += (p.x >> 8) & QMASK;
            se[1] += p.y & QMASK; so[1] += (p.y >> 8) & QMASK;
            se[2] += p.z & QMASK; so[2] += (p.z >> 8) & QMASK;
            se[3] += p.w & QMASK; so[3] += (p.w >> 8) & QMASK;
        }
        #pragma unroll
        for (int w = 0; w < 4; w++) {
            qe[w] += __shfl_xor(qe[w], 16, 64); qe[w] += __shfl_xor(qe[w], 32, 64);
            qo[w] += __shfl_xor(qo[w], 16, 64); qo[w] += __shfl_xor(qo[w], 32, 64);
            se[w] += __shfl_xor(se[w], 16, 64); se[w] += __shfl_xor(se[w], 32, 64);
            so[w] += __shfl_xor(so[w], 16, 64); so[w] += __shfl_xor(so[w], 32, 64);
        }
        // lanes 0..15: bias-correct (q = 32x+128), scale 1/32, pack f16 pairs
        if (lane < 16) {
            #pragma unroll
            for (int w = 0; w < 4; w++) {
                float tq0 = (float)((int)(qe[w] & 0xFFFFu) - 6400)  * 0.03125f;
                float tq1 = (float)((int)(qo[w] & 0xFFFFu) - 6400)  * 0.03125f;
                float tq2 = (float)((int)(qe[w] >> 16)     - 6400)  * 0.03125f;
                float tq3 = (float)((int)(qo[w] >> 16)     - 6400)  * 0.03125f;
                float ts0 = (float)((int)(se[w] & 0xFFFFu) - 12800) * 0.03125f;
                float ts1 = (float)((int)(so[w] & 0xFFFFu) - 12800) * 0.03125f;
                float ts2 = (float)((int)(se[w] >> 16)     - 12800) * 0.03125f;
                float ts3 = (float)((int)(so[w] >> 16)     - 12800) * 0.03125f;
                lds_t[wv * DIM4 + hl * 4 + w] =
                    make_uint4(pkh(tq0, tq1), pkh(tq2, tq3),
                               pkh(ts0, ts1), pkh(ts2, ts3));
            }
        }
    } else {
        const int* ip = &lds_idx[wv * CPAD];
        float4 aq  = make_float4(0.f, 0.f, 0.f, 0.f);
        float4 asv = make_float4(0.f, 0.f, 0.f, 0.f);
        #pragma unroll 10
        for (int e = 0; e < 50; e++) {
            float4 v = emb4[ip[e] * DIM4 + lane];
            aq.x += v.x; aq.y += v.y; aq.z += v.z; aq.w += v.w;
        }
        #pragma unroll 10
        for (int e = 50; e < 150; e++) {
            float4 v = emb4[ip[e] * DIM4 + lane];
            asv.x += v.x; asv.y += v.y; asv.z += v.z; asv.w += v.w;
        }
        lds_t[wv * DIM4 + lane] =
            make_uint4(pkh(aq.x, aq.y), pkh(aq.z, aq.w),
                       pkh(asv.x, asv.y), pkh(asv.z, asv.w));
    }
    __syncthreads();

    // ---- matmul: thread owns i = tid (0..255) and all 4 batch rows ----
    {
        const int i = tid;
        float accq [4] = {};
        float accsv[4] = {};
        #pragma unroll 4
        for (int j4 = 0; j4 < DIM4; j4++) {
            const uint4 wp = wpk[j4 * 256 + i];   // 1 coalesced dwordx4/thread
            #pragma unroll
            for (int r = 0; r < 4; r++) {
                const uint4 tp = lds_t[r * DIM4 + j4];  // uniform b128
                accq [r] = __builtin_amdgcn_fdot2(bch(wp.x), bch(tp.x), accq [r], false);
                accq [r] = __builtin_amdgcn_fdot2(bch(wp.y), bch(tp.y), accq [r], false);
                accsv[r] = __builtin_amdgcn_fdot2(bch(wp.z), bch(tp.z), accsv[r], false);
                accsv[r] = __builtin_amdgcn_fdot2(bch(wp.w), bch(tp.w), accsv[r], false);
            }
        }
        #pragma unroll
        for (int r = 0; r < 4; r++) {
            lds_gq [r * DIM + i] = accq [r];
            lds_gsv[r * DIM + i] = accsv[r];
        }
    }
    __syncthreads();

    // ---- epilogue: gates = c_s + sig(c_s*g_q) + sig(c_s*g_sv) ----
    // c_s from LDS (exact fp32) -> zero global reads after the barrier.
    {
        const float4* gq4 = (const float4*)lds_gq;
        const float4* gs4 = (const float4*)lds_gsv;
        float4* out4 = (float4*)out;
        #pragma unroll
        for (int t = tid; t < TBATCH * 4 * DIM4; t += BLK) {
            const int row = t >> 8;
            const int s   = (t >> 6) & 3;
            const int col = t & 63;
            const int b   = b0 + row;
            float4 cs;
            if (QU8) {
                cs = lds_cs[(t >> 6) * DIM4 + col];
            } else {
                const int slot = slot_names[b * 4 + s];
                cs = emb4[slot * DIM4 + col];
            }
            float4 gq = gq4[row * DIM4 + col];
            float4 gs = gs4[row * DIM4 + col];
            float4 g;
            g.x = cs.x + sigmoidf_(cs.x * gq.x) + sigmoidf_(cs.x * gs.x);
            g.y = cs.y + sigmoidf_(cs.y * gq.y) + sigmoidf_(cs.y * gs.y);
            g.z = cs.z + sigmoidf_(cs.z * gq.z) + sigmoidf_(cs.z * gs.z);
            g.w = cs.w + sigmoidf_(cs.w * gq.w) + sigmoidf_(cs.w * gs.w);
            out4[(b * 4 + s) * DIM4 + col] = g;
        }
    }
}

extern "C" void kernel_launch(void* const* d_in, const int* in_sizes, int n_in,
                              void* d_out, int out_size, void* d_ws, size_t ws_size,
                              hipStream_t stream) {
    const int*   acts_request = (const int*)  d_in[0];
    const int*   acts_slot    = (const int*)  d_in[1];
    const int*   acts_value   = (const int*)  d_in[2];
    const int*   slot_names   = (const int*)  d_in[3];
    const float* ontology_emb = (const float*)d_in[4];
    const float* w1           = (const float*)d_in[5];
    const float* w2           = (const float*)d_in[6];
    float*       out          = (float*)      d_out;

    const int bsz   = in_sizes[0] / LLEN;        // 4096
    const int nblk  = bsz / TBATCH;              // 1024
    const int nelem = in_sizes[4];               // V * 256 = 25,600,000

    const size_t q_bytes = (size_t)nelem;        // 25.6 MB
    const size_t w_bytes = (size_t)DIM4 * DIM * 16;  // 256 KB packed f16 tile
    const bool   use_q   = ws_size >= q_bytes + w_bytes;

    if (use_q) {
        uint4* embq = (uint4*)d_ws;
        uint4* wpk  = (uint4*)((char*)d_ws + q_bytes);
        const int conv_blocks = (nelem + (512 * 16) - 1) / (512 * 16);
        prep_kernel<<<32 + conv_blocks, 512, 0, stream>>>(
            w1, w2, ontology_emb, wpk, embq, nelem);
        slotgate_fused<true><<<nblk, BLK, 0, stream>>>(
            acts_request, acts_slot, acts_value, slot_names,
            ontology_emb, embq, wpk, out);
    } else {
        // fallback: fp32 gather, but still needs the 256 KB packed-w tile
        uint4* wpk = (uint4*)d_ws;
        prep_kernel<<<32, 512, 0, stream>>>(
            w1, w2, ontology_emb, wpk, (uint4*)d_ws, 0);
        slotgate_fused<false><<<nblk, BLK, 0, stream>>>(
            acts_request, acts_slot, acts_value, slot_names,
            ontology_emb, (const uint4*)d_ws, wpk, out);
    }
}